// Round 2
// baseline (456.852 us; speedup 1.0000x reference)
//
#include <hip/hip_runtime.h>
#include <stdint.h>

// ---------------- problem dims ----------------
#define B_DIM 64
#define P_DIM 225
#define K_DIM 16
#define D_DIM 640
#define M_REAL (B_DIM * P_DIM)   // 14400 query rows
#define N_REAL (K_DIM * P_DIM)   // 3600 reference rows

// ---------------- GEMM tiling ----------------
#define BM 128
#define BN 128
#define BKT 32
#define MTILES 113               // ceil(14400/128) -> Mpad 14464
#define NTILES 29                // ceil(3600/128)  -> Npad 3712
#define MPAD (MTILES * BM)
#define NPAD (NTILES * BN)
#define MCHUNK 15                // ceil(MTILES/8) per-XCD bm groups

typedef __bf16 bf16x8 __attribute__((ext_vector_type(8)));
typedef float f32x4 __attribute__((ext_vector_type(4)));

// ---------------- helpers ----------------
__device__ __forceinline__ unsigned short f2bf(float f) {
  union { float f; unsigned u; } v; v.f = f;
  unsigned u = v.u;
  return (unsigned short)((u + 0x7FFFu + ((u >> 16) & 1u)) >> 16);  // RNE
}

// monotone float -> uint key (order-preserving), for atomicMax on floats
__device__ __forceinline__ unsigned f2key(float f) {
  union { float f; unsigned u; } v; v.f = f;
  unsigned u = v.u;
  return (u & 0x80000000u) ? ~u : (u | 0x80000000u);
}
__device__ __forceinline__ float key2f(unsigned k) {
  unsigned b = (k & 0x80000000u) ? (k ^ 0x80000000u) : ~k;
  union { unsigned u; float f; } v; v.u = b;
  return v.f;
}

__device__ __forceinline__ void gl_lds16(const void* g, void* l) {
  __builtin_amdgcn_global_load_lds(
      (const __attribute__((address_space(1))) void*)g,
      (__attribute__((address_space(3))) void*)l,
      16, 0, 0);
}

// =====================================================================
// Kernel A: q-staging (+rowmax zero) | r-staging | adapter (one block)
//   blocks [0, MPAD/4)              : q rows, 4 per block
//   blocks [MPAD/4, MPAD/4+NPAD/4)  : r rows, 4 per block
//   last block                      : adapter favg = mean_k relu(relu(r_img@w1)@w2)
// =====================================================================
#define QBLKS (MPAD / 4)
#define RBLKS (NPAD / 4)
__global__ __launch_bounds__(256) void stage_all_kernel(
    const float* __restrict__ q, const float* __restrict__ r,
    const float* __restrict__ r_img,
    const float* __restrict__ aw1, const float* __restrict__ aw2,
    unsigned short* __restrict__ qb, unsigned short* __restrict__ rb,
    float* __restrict__ qinv, unsigned* __restrict__ rowmax,
    float* __restrict__ favg) {
  __shared__ float h1s[16 * 160];  // adapter hidden, 10 KB (only last block uses)
  const int blk = blockIdx.x;
  const int tid = threadIdx.x;

  if (blk < QBLKS) {
    int row = blk * 4 + (tid >> 6);
    int lane = tid & 63;
    if (lane == 0) rowmax[row] = 0u;  // key-space minimum
    unsigned short* dst = qb + (long)row * D_DIM;
    if (row >= M_REAL) {
#pragma unroll
      for (int i = 0; i < 10; i++) dst[i * 64 + lane] = 0;
      return;
    }
    const float* src = q + (long)row * D_DIM;
    float v[10];
    float ss = 0.f;
#pragma unroll
    for (int i = 0; i < 10; i++) { v[i] = src[i * 64 + lane]; ss += v[i] * v[i]; }
#pragma unroll
    for (int off = 32; off > 0; off >>= 1) ss += __shfl_xor(ss, off);
    float inv = 1.f / (sqrtf(ss) + 1e-6f);
    if (lane == 0) qinv[row] = inv;
#pragma unroll
    for (int i = 0; i < 10; i++) dst[i * 64 + lane] = f2bf(v[i]);
    return;
  }

  if (blk < QBLKS + RBLKS) {
    int row = (blk - QBLKS) * 4 + (tid >> 6);
    int lane = tid & 63;
    unsigned short* dst = rb + (long)row * D_DIM;
    if (row >= N_REAL) {
#pragma unroll
      for (int i = 0; i < 10; i++) dst[i * 64 + lane] = 0;
      return;
    }
    const float* src = r + (long)row * D_DIM;
    float v[10];
    float ss = 0.f;
#pragma unroll
    for (int i = 0; i < 10; i++) { v[i] = src[i * 64 + lane]; ss += v[i] * v[i]; }
#pragma unroll
    for (int off = 32; off > 0; off >>= 1) ss += __shfl_xor(ss, off);
    float sc = 1.f / (sqrtf(ss) + 1e-6f);
#pragma unroll
    for (int i = 0; i < 10; i++) dst[i * 64 + lane] = f2bf(v[i] * sc);
    return;
  }

  // ---- adapter block ----
  // stage 1: h1[k][j] = relu(r_img[k] . w1[:,j]),  k<16, j<160
  for (int e = tid; e < 16 * 160; e += 256) {
    int k = e / 160, j = e - k * 160;
    const float* rk = r_img + k * D_DIM;
    float a0 = 0.f, a1 = 0.f, a2 = 0.f, a3 = 0.f;
    for (int d = 0; d < D_DIM; d += 4) {
      a0 += rk[d + 0] * aw1[(d + 0) * 160 + j];
      a1 += rk[d + 1] * aw1[(d + 1) * 160 + j];
      a2 += rk[d + 2] * aw1[(d + 2) * 160 + j];
      a3 += rk[d + 3] * aw1[(d + 3) * 160 + j];
    }
    h1s[e] = fmaxf(a0 + a1 + a2 + a3, 0.f);
  }
  __syncthreads();
  // stage 2: favg[d] = mean_k relu(h1 @ w2)[k][d]
  for (int d = tid; d < D_DIM; d += 256) {
    float a[K_DIM];
#pragma unroll
    for (int k = 0; k < K_DIM; k++) a[k] = 0.f;
    for (int j = 0; j < 160; j++) {
      float w = aw2[j * D_DIM + d];
#pragma unroll
      for (int k = 0; k < K_DIM; k++) a[k] += h1s[k * 160 + j] * w;
    }
    float s = 0.f;
#pragma unroll
    for (int k = 0; k < K_DIM; k++) s += fmaxf(a[k], 0.f);
    favg[d] = s * (1.f / 16.f);
  }
}

// =====================================================================
// Kernel B: fused bf16 MFMA GEMM + row-max, XCD-ownership swizzle
// =====================================================================
__global__ __launch_bounds__(256) void sim_max_kernel(
    const unsigned short* __restrict__ Qb,
    const unsigned short* __restrict__ Rb,
    unsigned* __restrict__ rowmax) {
  __shared__ __attribute__((aligned(16))) unsigned short As[BM * BKT];  // 8 KB
  __shared__ __attribute__((aligned(16))) unsigned short Bs[BN * BKT];  // 8 KB

  // XCD-ownership swizzle: xcd owns bm = {xcd, xcd+8, ...}, bn fastest.
  const int xcd = blockIdx.x & 7;
  const int idx = blockIdx.x >> 3;
  const int bm = xcd + 8 * (idx / NTILES);
  const int bn = idx % NTILES;
  if (bm >= MTILES) return;

  const int tid = threadIdx.x;
  const int wave = tid >> 6, lane = tid & 63;
  const int wr = wave >> 1, wc = wave & 1;
  const int q = lane >> 4, m0 = lane & 15;

  // staging geometry: chunk c of wave -> LDS bytes [((wave*2+c)*64+lane)*16, +16)
  const int fA0 = ((wave * 2 + 0) * 64 + lane) * 16;
  const int fA1 = ((wave * 2 + 1) * 64 + lane) * 16;
  const int rowA0 = fA0 >> 6, colA0 = (fA0 & 63) >> 1;  // row stride 32 bf16 = 64 B
  const int rowA1 = fA1 >> 6, colA1 = (fA1 & 63) >> 1;

  const int aBase = bm * BM;
  const int bBase = bn * BN;

  f32x4 zero = {0.f, 0.f, 0.f, 0.f};
  f32x4 acc[4][4];
#pragma unroll
  for (int i = 0; i < 4; i++)
#pragma unroll
    for (int j = 0; j < 4; j++) acc[i][j] = zero;

  for (int k0 = 0; k0 < D_DIM; k0 += BKT) {
    gl_lds16(Qb + (aBase + rowA0) * D_DIM + k0 + colA0, &As[fA0 / 2]);
    gl_lds16(Qb + (aBase + rowA1) * D_DIM + k0 + colA1, &As[fA1 / 2]);
    gl_lds16(Rb + (bBase + rowA0) * D_DIM + k0 + colA0, &Bs[fA0 / 2]);
    gl_lds16(Rb + (bBase + rowA1) * D_DIM + k0 + colA1, &Bs[fA1 / 2]);
    __syncthreads();  // drains vmcnt -> LDS tiles ready

    bf16x8 af[4], bfr[4];
#pragma unroll
    for (int mi = 0; mi < 4; mi++)
      af[mi] = *(const bf16x8*)&As[(wr * 64 + mi * 16 + m0) * BKT + q * 8];
#pragma unroll
    for (int ni = 0; ni < 4; ni++)
      bfr[ni] = *(const bf16x8*)&Bs[(wc * 64 + ni * 16 + m0) * BKT + q * 8];
#pragma unroll
    for (int mi = 0; mi < 4; mi++)
#pragma unroll
      for (int ni = 0; ni < 4; ni++)
        acc[mi][ni] = __builtin_amdgcn_mfma_f32_16x16x32_bf16(
            af[mi], bfr[ni], acc[mi][ni], 0, 0, 0);
    __syncthreads();  // protect LDS before next-iter overwrite
  }

  // epilogue: per-row max over this block's 128 columns, then global atomicMax
  const int colBase = bn * BN + wc * 64;
#pragma unroll
  for (int mi = 0; mi < 4; mi++) {
    float rmax[4] = {-3.0e38f, -3.0e38f, -3.0e38f, -3.0e38f};
#pragma unroll
    for (int ni = 0; ni < 4; ni++) {
      bool valid = (colBase + ni * 16 + m0) < N_REAL;
#pragma unroll
      for (int r = 0; r < 4; r++) {
        float v = valid ? acc[mi][ni][r] : -3.0e38f;
        rmax[r] = fmaxf(rmax[r], v);
      }
    }
#pragma unroll
    for (int r = 0; r < 4; r++) {
      float v = rmax[r];
      v = fmaxf(v, __shfl_xor(v, 1));
      v = fmaxf(v, __shfl_xor(v, 2));
      v = fmaxf(v, __shfl_xor(v, 4));
      v = fmaxf(v, __shfl_xor(v, 8));
      rmax[r] = v;
    }
    if (m0 == 0) {
      int row = bm * BM + wr * 64 + mi * 16 + q * 4;
#pragma unroll
      for (int r = 0; r < 4; r++)
        atomicMax(&rowmax[row + r], f2key(rmax[r]));
    }
  }
}

// =====================================================================
// Kernel C: finale — per batch element b: amap + amean + s_map head +
//           s_ref head + final score. 64 blocks x 256.
// =====================================================================
__global__ __launch_bounds__(256) void finale_kernel(
    const unsigned* __restrict__ rowmax, const float* __restrict__ qinv,
    const float* __restrict__ q_img, const float* __restrict__ favg,
    const float* __restrict__ hw1, const float* __restrict__ hb1,
    const float* __restrict__ hg2, const float* __restrict__ hbe2,
    const float* __restrict__ hw2, const float* __restrict__ hb2,
    const float* __restrict__ hg3, const float* __restrict__ hbe3,
    const float* __restrict__ hw3, const float* __restrict__ hb3,
    const float* __restrict__ rw1, const float* __restrict__ rb1,
    const float* __restrict__ rg2, const float* __restrict__ rbe2,
    const float* __restrict__ rw2, const float* __restrict__ rb2,
    const float* __restrict__ rg3, const float* __restrict__ rbe3,
    const float* __restrict__ rw3, const float* __restrict__ rb3,
    float* __restrict__ out) {
  int b = blockIdx.x, t = threadIdx.x;
  __shared__ float amap[P_DIM];
  __shared__ float red[256];
  __shared__ float x[D_DIM];
  __shared__ float h1s[128];
  __shared__ float h2s[64];
  __shared__ float smap_s, amean_s;

  // amap + x load
  float av = 0.f;
  if (t < P_DIM) {
    int row = b * P_DIM + t;
    float mx = key2f(rowmax[row]);
    av = 0.5f * (1.f - mx * qinv[row]);
    amap[t] = av;
  }
  red[t] = av;
  for (int d = t; d < D_DIM; d += 256) x[d] = q_img[b * D_DIM + d] - favg[d];
  __syncthreads();
  for (int s = 128; s > 0; s >>= 1) {
    if (t < s) red[t] += red[t + s];
    __syncthreads();
  }
  if (t == 0) amean_s = red[0] * (1.f / 225.f);

  // ---- s_map head (input amap, 225) ----
  if (t < 128) {
    float a0 = hb1[t], a1 = 0.f, a2 = 0.f;
    for (int p = 0; p < P_DIM; p += 3) {  // 225 = 75*3
      a0 += amap[p + 0] * hw1[(p + 0) * 128 + t];
      a1 += amap[p + 1] * hw1[(p + 1) * 128 + t];
      a2 += amap[p + 2] * hw1[(p + 2) * 128 + t];
    }
    float a = a0 + a1 + a2;
    h1s[t] = fmaxf(a, 0.f) * hg2[t] + hbe2[t];
  }
  __syncthreads();
  if (t < 64) {
    float a = hb2[t];
    for (int j = 0; j < 128; j++) a += h1s[j] * hw2[j * 64 + t];
    h2s[t] = fmaxf(a, 0.f) * hg3[t] + hbe3[t];
  }
  __syncthreads();
  if (t < 64) {
    float p = h2s[t] * hw3[t];
    p += __shfl_xor(p, 32); p += __shfl_xor(p, 16); p += __shfl_xor(p, 8);
    p += __shfl_xor(p, 4);  p += __shfl_xor(p, 2);  p += __shfl_xor(p, 1);
    if (t == 0) smap_s = 1.f / (1.f + expf(-(p + hb3[0])));
  }
  __syncthreads();

  // ---- s_ref head (input x, 640) ----
  if (t < 128) {
    float a0 = rb1[t], a1 = 0.f, a2 = 0.f, a3 = 0.f;
    for (int d = 0; d < D_DIM; d += 4) {
      a0 += x[d + 0] * rw1[(d + 0) * 128 + t];
      a1 += x[d + 1] * rw1[(d + 1) * 128 + t];
      a2 += x[d + 2] * rw1[(d + 2) * 128 + t];
      a3 += x[d + 3] * rw1[(d + 3) * 128 + t];
    }
    float a = a0 + a1 + a2 + a3;
    h1s[t] = fmaxf(a, 0.f) * rg2[t] + rbe2[t];
  }
  __syncthreads();
  if (t < 64) {
    float a = rb2[t];
    for (int j = 0; j < 128; j++) a += h1s[j] * rw2[j * 64 + t];
    h2s[t] = fmaxf(a, 0.f) * rg3[t] + rbe3[t];
  }
  __syncthreads();
  if (t < 64) {
    float p = h2s[t] * rw3[t];
    p += __shfl_xor(p, 32); p += __shfl_xor(p, 16); p += __shfl_xor(p, 8);
    p += __shfl_xor(p, 4);  p += __shfl_xor(p, 2);  p += __shfl_xor(p, 1);
    if (t == 0) {
      float sref = 1.f / (1.f + expf(-(p + rb3[0])));
      out[b] = 0.5f * (sref + smap_s) + amean_s;
    }
  }
}

// ---------------- launch ----------------
extern "C" void kernel_launch(void* const* d_in, const int* in_sizes, int n_in,
                              void* d_out, int out_size, void* d_ws, size_t ws_size,
                              hipStream_t stream) {
  const float* q_patch = (const float*)d_in[0];
  const float* r_patch = (const float*)d_in[1];
  const float* q_img   = (const float*)d_in[2];
  const float* r_img   = (const float*)d_in[3];
  const float* adpt_w1 = (const float*)d_in[4];
  const float* adpt_w2 = (const float*)d_in[5];
  const float* dh_w1 = (const float*)d_in[6];
  const float* dh_b1 = (const float*)d_in[7];
  const float* dh_g2 = (const float*)d_in[8];
  const float* dh_be2 = (const float*)d_in[9];
  const float* dh_w2 = (const float*)d_in[10];
  const float* dh_b2 = (const float*)d_in[11];
  const float* dh_g3 = (const float*)d_in[12];
  const float* dh_be3 = (const float*)d_in[13];
  const float* dh_w3 = (const float*)d_in[14];
  const float* dh_b3 = (const float*)d_in[15];
  const float* dr_w1 = (const float*)d_in[16];
  const float* dr_b1 = (const float*)d_in[17];
  const float* dr_g2 = (const float*)d_in[18];
  const float* dr_be2 = (const float*)d_in[19];
  const float* dr_w2 = (const float*)d_in[20];
  const float* dr_b2 = (const float*)d_in[21];
  const float* dr_g3 = (const float*)d_in[22];
  const float* dr_be3 = (const float*)d_in[23];
  const float* dr_w3 = (const float*)d_in[24];
  const float* dr_b3 = (const float*)d_in[25];

  // ws layout (bytes)
  const size_t QB_BYTES = (size_t)MPAD * D_DIM * 2;      // 18,513,920
  const size_t RB_BYTES = (size_t)NPAD * D_DIM * 2;      //  4,751,360
  char* ws = (char*)d_ws;
  unsigned short* qb = (unsigned short*)(ws);
  unsigned short* rb = (unsigned short*)(ws + QB_BYTES);
  float* qinv        = (float*)(ws + QB_BYTES + RB_BYTES);
  unsigned* rowmax   = (unsigned*)(ws + QB_BYTES + RB_BYTES + (size_t)M_REAL * 4);
  float* favg        = (float*)(ws + QB_BYTES + RB_BYTES + (size_t)M_REAL * 4 + (size_t)MPAD * 4);

  stage_all_kernel<<<QBLKS + RBLKS + 1, 256, 0, stream>>>(
      q_patch, r_patch, r_img, adpt_w1, adpt_w2, qb, rb, qinv, rowmax, favg);
  sim_max_kernel<<<8 * MCHUNK * NTILES, 256, 0, stream>>>(qb, rb, rowmax);
  finale_kernel<<<B_DIM, 256, 0, stream>>>(
      rowmax, qinv, q_img, favg,
      dh_w1, dh_b1, dh_g2, dh_be2, dh_w2, dh_b2, dh_g3, dh_be3, dh_w3, dh_b3,
      dr_w1, dr_b1, dr_g2, dr_be2, dr_w2, dr_b2, dr_g3, dr_be3, dr_w3, dr_b3,
      (float*)d_out);
}

// Round 3
// 346.073 us; speedup vs baseline: 1.3201x; 1.3201x over previous
//
#include <hip/hip_runtime.h>
#include <stdint.h>

// ---------------- problem dims ----------------
#define B_DIM 64
#define P_DIM 225
#define K_DIM 16
#define D_DIM 640
#define M_REAL (B_DIM * P_DIM)   // 14400 query rows
#define N_REAL (K_DIM * P_DIM)   // 3600 reference rows

// ---------------- GEMM tiling ----------------
#define BM 128
#define BN 128
#define BKT 32
#define MTILES 113               // ceil(14400/128) -> Mpad 14464
#define NTILES 29                // ceil(3600/128)  -> Npad 3712
#define MPAD (MTILES * BM)
#define NPAD (NTILES * BN)
#define MCHUNK 15                // ceil(MTILES/8) per-XCD bm groups

typedef __bf16 bf16x8 __attribute__((ext_vector_type(8)));
typedef float f32x4 __attribute__((ext_vector_type(4)));

// ---------------- helpers ----------------
__device__ __forceinline__ unsigned short f2bf(float f) {
  union { float f; unsigned u; } v; v.f = f;
  unsigned u = v.u;
  return (unsigned short)((u + 0x7FFFu + ((u >> 16) & 1u)) >> 16);  // RNE
}

// monotone float -> uint key (order-preserving), for atomicMax on floats
__device__ __forceinline__ unsigned f2key(float f) {
  union { float f; unsigned u; } v; v.f = f;
  unsigned u = v.u;
  return (u & 0x80000000u) ? ~u : (u | 0x80000000u);
}
__device__ __forceinline__ float key2f(unsigned k) {
  unsigned b = (k & 0x80000000u) ? (k ^ 0x80000000u) : ~k;
  union { unsigned u; float f; } v; v.u = b;
  return v.f;
}

__device__ __forceinline__ void gl_lds16(const void* g, void* l) {
  __builtin_amdgcn_global_load_lds(
      (const __attribute__((address_space(1))) void*)g,
      (__attribute__((address_space(3))) void*)l,
      16, 0, 0);
}

// =====================================================================
// Kernel A: q-staging (+rowmax zero) | r-staging | adapter stage 1
//   blocks [0, QBLKS)            : q rows, 4 per block
//   blocks [QBLKS, QBLKS+RBLKS)  : r rows, 4 per block
//   last 4 blocks                : h1[k][j] = relu(r_img[k] . w1[:,j])
//                                  one wave per k, lanes own j columns
// =====================================================================
#define QBLKS (MPAD / 4)
#define RBLKS (NPAD / 4)
__global__ __launch_bounds__(256) void stage_all_kernel(
    const float* __restrict__ q, const float* __restrict__ r,
    const float* __restrict__ r_img, const float* __restrict__ aw1,
    unsigned short* __restrict__ qb, unsigned short* __restrict__ rb,
    float* __restrict__ qinv, unsigned* __restrict__ rowmax,
    float* __restrict__ h1) {
  const int blk = blockIdx.x;
  const int tid = threadIdx.x;

  if (blk < QBLKS) {
    int row = blk * 4 + (tid >> 6);
    int lane = tid & 63;
    if (lane == 0) rowmax[row] = 0u;  // key-space minimum
    unsigned short* dst = qb + (long)row * D_DIM;
    if (row >= M_REAL) {
#pragma unroll
      for (int i = 0; i < 10; i++) dst[i * 64 + lane] = 0;
      return;
    }
    const float* src = q + (long)row * D_DIM;
    float v[10];
    float ss = 0.f;
#pragma unroll
    for (int i = 0; i < 10; i++) { v[i] = src[i * 64 + lane]; ss += v[i] * v[i]; }
#pragma unroll
    for (int off = 32; off > 0; off >>= 1) ss += __shfl_xor(ss, off);
    float inv = 1.f / (sqrtf(ss) + 1e-6f);
    if (lane == 0) qinv[row] = inv;
#pragma unroll
    for (int i = 0; i < 10; i++) dst[i * 64 + lane] = f2bf(v[i]);
    return;
  }

  if (blk < QBLKS + RBLKS) {
    int row = (blk - QBLKS) * 4 + (tid >> 6);
    int lane = tid & 63;
    unsigned short* dst = rb + (long)row * D_DIM;
    if (row >= N_REAL) {
#pragma unroll
      for (int i = 0; i < 10; i++) dst[i * 64 + lane] = 0;
      return;
    }
    const float* src = r + (long)row * D_DIM;
    float v[10];
    float ss = 0.f;
#pragma unroll
    for (int i = 0; i < 10; i++) { v[i] = src[i * 64 + lane]; ss += v[i] * v[i]; }
#pragma unroll
    for (int off = 32; off > 0; off >>= 1) ss += __shfl_xor(ss, off);
    float sc = 1.f / (sqrtf(ss) + 1e-6f);
#pragma unroll
    for (int i = 0; i < 10; i++) dst[i * 64 + lane] = f2bf(v[i] * sc);
    return;
  }

  // ---- adapter stage 1: one wave per k ----
  {
    int a = blk - (QBLKS + RBLKS);       // 0..3
    int wave = tid >> 6, lane = tid & 63;
    int k = a * 4 + wave;                // 0..15
    const float* rk = r_img + k * D_DIM;
    int j0 = lane, j1 = lane + 64, j2 = 128 + (lane & 31);  // j2 duplicated hi lanes
    float a0 = 0.f, a1 = 0.f, a2 = 0.f;
    for (int d = 0; d < D_DIM; d += 4) {
#pragma unroll
      for (int u = 0; u < 4; u++) {
        float rv = rk[d + u];
        const float* wrow = aw1 + (d + u) * 160;
        a0 += rv * wrow[j0];
        a1 += rv * wrow[j1];
        a2 += rv * wrow[j2];
      }
    }
    float* hk = h1 + k * 160;
    hk[j0] = fmaxf(a0, 0.f);
    hk[j1] = fmaxf(a1, 0.f);
    if (lane < 32) hk[j2] = fmaxf(a2, 0.f);
  }
}

// =====================================================================
// Kernel B: fused bf16 MFMA GEMM + row-max, XCD-ownership swizzle
// =====================================================================
__global__ __launch_bounds__(256) void sim_max_kernel(
    const unsigned short* __restrict__ Qb,
    const unsigned short* __restrict__ Rb,
    unsigned* __restrict__ rowmax) {
  __shared__ __attribute__((aligned(16))) unsigned short As[BM * BKT];  // 8 KB
  __shared__ __attribute__((aligned(16))) unsigned short Bs[BN * BKT];  // 8 KB

  // XCD-ownership swizzle: xcd owns bm = {xcd, xcd+8, ...}, bn fastest.
  const int xcd = blockIdx.x & 7;
  const int idx = blockIdx.x >> 3;
  const int bm = xcd + 8 * (idx / NTILES);
  const int bn = idx % NTILES;
  if (bm >= MTILES) return;

  const int tid = threadIdx.x;
  const int wave = tid >> 6, lane = tid & 63;
  const int wr = wave >> 1, wc = wave & 1;
  const int q = lane >> 4, m0 = lane & 15;

  // staging geometry: chunk c of wave -> LDS bytes [((wave*2+c)*64+lane)*16, +16)
  const int fA0 = ((wave * 2 + 0) * 64 + lane) * 16;
  const int fA1 = ((wave * 2 + 1) * 64 + lane) * 16;
  const int rowA0 = fA0 >> 6, colA0 = (fA0 & 63) >> 1;  // row stride 32 bf16 = 64 B
  const int rowA1 = fA1 >> 6, colA1 = (fA1 & 63) >> 1;

  const int aBase = bm * BM;
  const int bBase = bn * BN;

  f32x4 zero = {0.f, 0.f, 0.f, 0.f};
  f32x4 acc[4][4];
#pragma unroll
  for (int i = 0; i < 4; i++)
#pragma unroll
    for (int j = 0; j < 4; j++) acc[i][j] = zero;

  for (int k0 = 0; k0 < D_DIM; k0 += BKT) {
    gl_lds16(Qb + (aBase + rowA0) * D_DIM + k0 + colA0, &As[fA0 / 2]);
    gl_lds16(Qb + (aBase + rowA1) * D_DIM + k0 + colA1, &As[fA1 / 2]);
    gl_lds16(Rb + (bBase + rowA0) * D_DIM + k0 + colA0, &Bs[fA0 / 2]);
    gl_lds16(Rb + (bBase + rowA1) * D_DIM + k0 + colA1, &Bs[fA1 / 2]);
    __syncthreads();  // drains vmcnt -> LDS tiles ready

    bf16x8 af[4], bfr[4];
#pragma unroll
    for (int mi = 0; mi < 4; mi++)
      af[mi] = *(const bf16x8*)&As[(wr * 64 + mi * 16 + m0) * BKT + q * 8];
#pragma unroll
    for (int ni = 0; ni < 4; ni++)
      bfr[ni] = *(const bf16x8*)&Bs[(wc * 64 + ni * 16 + m0) * BKT + q * 8];
#pragma unroll
    for (int mi = 0; mi < 4; mi++)
#pragma unroll
      for (int ni = 0; ni < 4; ni++)
        acc[mi][ni] = __builtin_amdgcn_mfma_f32_16x16x32_bf16(
            af[mi], bfr[ni], acc[mi][ni], 0, 0, 0);
    __syncthreads();  // protect LDS before next-iter overwrite
  }

  // epilogue: per-row max over this block's 128 columns, then global atomicMax
  const int colBase = bn * BN + wc * 64;
#pragma unroll
  for (int mi = 0; mi < 4; mi++) {
    float rmax[4] = {-3.0e38f, -3.0e38f, -3.0e38f, -3.0e38f};
#pragma unroll
    for (int ni = 0; ni < 4; ni++) {
      bool valid = (colBase + ni * 16 + m0) < N_REAL;
#pragma unroll
      for (int r = 0; r < 4; r++) {
        float v = valid ? acc[mi][ni][r] : -3.0e38f;
        rmax[r] = fmaxf(rmax[r], v);
      }
    }
#pragma unroll
    for (int r = 0; r < 4; r++) {
      float v = rmax[r];
      v = fmaxf(v, __shfl_xor(v, 1));
      v = fmaxf(v, __shfl_xor(v, 2));
      v = fmaxf(v, __shfl_xor(v, 4));
      v = fmaxf(v, __shfl_xor(v, 8));
      rmax[r] = v;
    }
    if (m0 == 0) {
      int row = bm * BM + wr * 64 + mi * 16 + q * 4;
#pragma unroll
      for (int r = 0; r < 4; r++)
        atomicMax(&rowmax[row + r], f2key(rmax[r]));
    }
  }
}

// =====================================================================
// Kernel C: finale — per batch element b:
//   amap + amean + s_map head + (favg from h1, redundant per block) +
//   s_ref head + final score. 64 blocks x 256.
// =====================================================================
__global__ __launch_bounds__(256) void finale_kernel(
    const unsigned* __restrict__ rowmax, const float* __restrict__ qinv,
    const float* __restrict__ q_img, const float* __restrict__ h1,
    const float* __restrict__ aw2,
    const float* __restrict__ hw1, const float* __restrict__ hb1,
    const float* __restrict__ hg2, const float* __restrict__ hbe2,
    const float* __restrict__ hw2, const float* __restrict__ hb2,
    const float* __restrict__ hg3, const float* __restrict__ hbe3,
    const float* __restrict__ hw3, const float* __restrict__ hb3,
    const float* __restrict__ rw1, const float* __restrict__ rb1,
    const float* __restrict__ rg2, const float* __restrict__ rbe2,
    const float* __restrict__ rw2, const float* __restrict__ rb2,
    const float* __restrict__ rg3, const float* __restrict__ rbe3,
    const float* __restrict__ rw3, const float* __restrict__ rb3,
    float* __restrict__ out) {
  int b = blockIdx.x, t = threadIdx.x;
  __shared__ float h1a[16 * 160];   // adapter hidden (10 KB)
  __shared__ float amap[P_DIM];
  __shared__ float red[256];
  __shared__ float x[D_DIM];
  __shared__ float h1s[128];
  __shared__ float h2s[64];
  __shared__ float smap_s;

  // load adapter hidden into LDS
#pragma unroll
  for (int i = 0; i < 10; i++) h1a[i * 256 + t] = h1[i * 256 + t];

  // amap
  float av = 0.f;
  if (t < P_DIM) {
    int row = b * P_DIM + t;
    float mx = key2f(rowmax[row]);
    av = 0.5f * (1.f - mx * qinv[row]);
    amap[t] = av;
  }
  red[t] = av;
  __syncthreads();
  for (int s = 128; s > 0; s >>= 1) {
    if (t < s) red[t] += red[t + s];
    __syncthreads();
  }
  float amean = red[0] * (1.f / 225.f);  // uniform after reduction

  // ---- s_map head (input amap, 225) ----
  if (t < 128) {
    float a0 = hb1[t], a1 = 0.f, a2 = 0.f;
    for (int p = 0; p < P_DIM; p += 3) {  // 225 = 75*3
      a0 += amap[p + 0] * hw1[(p + 0) * 128 + t];
      a1 += amap[p + 1] * hw1[(p + 1) * 128 + t];
      a2 += amap[p + 2] * hw1[(p + 2) * 128 + t];
    }
    float a = a0 + a1 + a2;
    h1s[t] = fmaxf(a, 0.f) * hg2[t] + hbe2[t];
  }
  __syncthreads();
  if (t < 64) {
    float a = hb2[t];
    for (int j = 0; j < 128; j++) a += h1s[j] * hw2[j * 64 + t];
    h2s[t] = fmaxf(a, 0.f) * hg3[t] + hbe3[t];
  }
  __syncthreads();
  if (t < 64) {
    float p = h2s[t] * hw3[t];
    p += __shfl_xor(p, 32); p += __shfl_xor(p, 16); p += __shfl_xor(p, 8);
    p += __shfl_xor(p, 4);  p += __shfl_xor(p, 2);  p += __shfl_xor(p, 1);
    if (t == 0) smap_s = 1.f / (1.f + expf(-(p + hb3[0])));
  }
  __syncthreads();

  // ---- adapter stage 2 (redundant per block): x[d] = q_img[b][d] - favg[d]
  for (int d = t; d < D_DIM; d += 256) {
    float a[K_DIM];
#pragma unroll
    for (int k = 0; k < K_DIM; k++) a[k] = 0.f;
    for (int j = 0; j < 160; j++) {
      float w = aw2[j * D_DIM + d];
#pragma unroll
      for (int k = 0; k < K_DIM; k++) a[k] += h1a[k * 160 + j] * w;
    }
    float s = 0.f;
#pragma unroll
    for (int k = 0; k < K_DIM; k++) s += fmaxf(a[k], 0.f);
    x[d] = q_img[b * D_DIM + d] - s * (1.f / 16.f);
  }
  __syncthreads();

  // ---- s_ref head (input x, 640) ----
  if (t < 128) {
    float a0 = rb1[t], a1 = 0.f, a2 = 0.f, a3 = 0.f;
    for (int d = 0; d < D_DIM; d += 4) {
      a0 += x[d + 0] * rw1[(d + 0) * 128 + t];
      a1 += x[d + 1] * rw1[(d + 1) * 128 + t];
      a2 += x[d + 2] * rw1[(d + 2) * 128 + t];
      a3 += x[d + 3] * rw1[(d + 3) * 128 + t];
    }
    float a = a0 + a1 + a2 + a3;
    h1s[t] = fmaxf(a, 0.f) * rg2[t] + rbe2[t];
  }
  __syncthreads();
  if (t < 64) {
    float a = rb2[t];
    for (int j = 0; j < 128; j++) a += h1s[j] * rw2[j * 64 + t];
    h2s[t] = fmaxf(a, 0.f) * rg3[t] + rbe3[t];
  }
  __syncthreads();
  if (t < 64) {
    float p = h2s[t] * rw3[t];
    p += __shfl_xor(p, 32); p += __shfl_xor(p, 16); p += __shfl_xor(p, 8);
    p += __shfl_xor(p, 4);  p += __shfl_xor(p, 2);  p += __shfl_xor(p, 1);
    if (t == 0) {
      float sref = 1.f / (1.f + expf(-(p + rb3[0])));
      out[b] = 0.5f * (sref + smap_s) + amean;
    }
  }
}

// ---------------- launch ----------------
extern "C" void kernel_launch(void* const* d_in, const int* in_sizes, int n_in,
                              void* d_out, int out_size, void* d_ws, size_t ws_size,
                              hipStream_t stream) {
  const float* q_patch = (const float*)d_in[0];
  const float* r_patch = (const float*)d_in[1];
  const float* q_img   = (const float*)d_in[2];
  const float* r_img   = (const float*)d_in[3];
  const float* adpt_w1 = (const float*)d_in[4];
  const float* adpt_w2 = (const float*)d_in[5];
  const float* dh_w1 = (const float*)d_in[6];
  const float* dh_b1 = (const float*)d_in[7];
  const float* dh_g2 = (const float*)d_in[8];
  const float* dh_be2 = (const float*)d_in[9];
  const float* dh_w2 = (const float*)d_in[10];
  const float* dh_b2 = (const float*)d_in[11];
  const float* dh_g3 = (const float*)d_in[12];
  const float* dh_be3 = (const float*)d_in[13];
  const float* dh_w3 = (const float*)d_in[14];
  const float* dh_b3 = (const float*)d_in[15];
  const float* dr_w1 = (const float*)d_in[16];
  const float* dr_b1 = (const float*)d_in[17];
  const float* dr_g2 = (const float*)d_in[18];
  const float* dr_be2 = (const float*)d_in[19];
  const float* dr_w2 = (const float*)d_in[20];
  const float* dr_b2 = (const float*)d_in[21];
  const float* dr_g3 = (const float*)d_in[22];
  const float* dr_be3 = (const float*)d_in[23];
  const float* dr_w3 = (const float*)d_in[24];
  const float* dr_b3 = (const float*)d_in[25];

  // ws layout (bytes)
  const size_t QB_BYTES = (size_t)MPAD * D_DIM * 2;      // 18,513,920
  const size_t RB_BYTES = (size_t)NPAD * D_DIM * 2;      //  4,751,360
  char* ws = (char*)d_ws;
  unsigned short* qb = (unsigned short*)(ws);
  unsigned short* rb = (unsigned short*)(ws + QB_BYTES);
  float* qinv        = (float*)(ws + QB_BYTES + RB_BYTES);
  unsigned* rowmax   = (unsigned*)(ws + QB_BYTES + RB_BYTES + (size_t)M_REAL * 4);
  float* h1          = (float*)(ws + QB_BYTES + RB_BYTES + (size_t)M_REAL * 4 + (size_t)MPAD * 4);

  stage_all_kernel<<<QBLKS + RBLKS + 4, 256, 0, stream>>>(
      q_patch, r_patch, r_img, adpt_w1, qb, rb, qinv, rowmax, h1);
  sim_max_kernel<<<8 * MCHUNK * NTILES, 256, 0, stream>>>(qb, rb, rowmax);
  finale_kernel<<<B_DIM, 256, 0, stream>>>(
      rowmax, qinv, q_img, h1, adpt_w2,
      dh_w1, dh_b1, dh_g2, dh_be2, dh_w2, dh_b2, dh_g3, dh_be3, dh_w3, dh_b3,
      dr_w1, dr_b1, dr_g2, dr_be2, dr_w2, dr_b2, dr_g3, dr_be3, dr_w3, dr_b3,
      (float*)d_out);
}